// Round 4
// baseline (60.984 us; speedup 1.0000x reference)
//
#include <hip/hip_runtime.h>

// RoPE, fp32, d_k=128, theta=10000.
// out[..,2k]   = cos(a)*x[..,2k] - sin(a)*x[..,2k+1]
// out[..,2k+1] = sin(a)*x[..,2k] + cos(a)*x[..,2k+1],  a = pos[s]*theta^(-k/64)
//
// v3b: max-bandwidth falsification probe (compile-fixed: nontemporal
// builtins need native clang vector types, not HIP_vector_type<float,4>).
// Evidence so far: v1 (heavy VALU, 1 ld/st per thread) and v2 (1/4 trig,
// 4 ld/st per thread) both measure 61.0/60.9 us, while rocprof shows the
// top dispatches are the harness's 256 MiB workspace-poison fills
// (40.2 us @ 6.6 TB/s each) -- our kernel is <40 us and by roofline
// (16.8 MB traffic) should be ~3-6 us. Theory: score = ~40 us fill
// + ~15 us graph/launch overhead + ~5 us kernel.
// Levers in this version:
//   - one float4 per thread, exact grid (2048 blocks = 8 blocks/CU ramp)
//   - zero integer division: seq=4096 is pow2 -> s = (i>>5) & (seq-1)
//   - nontemporal load/store: stream is never re-read -> skip cache alloc
// If dur_us is again ~60.9, the harness floor is confirmed -> roofline.
//
// Trig via hardware v_sin_f32/v_cos_f32 in the REVOLUTIONS domain:
//   rev = (pos/2pi) * theta^(-k/64);  r = fract(rev);  sin(2*pi*r)
// Explicit fract required: |rev| can reach ~651, outside HW valid range.
// Precision verified: absmax 0.0156 vs 0.114 threshold.

#define D_K 128

typedef float vf4 __attribute__((ext_vector_type(4)));

template <bool POW2>
__global__ __launch_bounds__(256) void rope_kernel(
    const vf4* __restrict__ x4,
    const int* __restrict__ pos,
    vf4*       __restrict__ out4,
    int n4,
    int seq_or_mask)   // POW2: seq-1 ; else: seq
{
    int i = blockIdx.x * blockDim.x + threadIdx.x;
    if (i >= n4) return;

    int d4  = i & (D_K / 4 - 1);       // float4 index within head dim: 0..31
    int row = i >> 5;                  // (batch, token) row index
    int s   = POW2 ? (row & seq_or_mask) : (row % seq_or_mask);

    // p_rev = pos / (2*pi)
    float p_rev = (float)pos[s] * 0.15915494309189535f;

    // inv_freq(k) = theta^(-k/64) = exp2(-k * log2(theta)/64)
    const float L    = 0.20762050593046014f;   // log2(10000)/64
    const float STEP = 0.86596432336006535f;   // theta^(-1/64) = exp2(-L)
    int   k0 = d4 << 1;                        // pair index of .x/.y
    float f0 = __builtin_amdgcn_exp2f(-L * (float)k0);
    float f1 = f0 * STEP;

    float r0 = __builtin_amdgcn_fractf(p_rev * f0);
    float r1 = __builtin_amdgcn_fractf(p_rev * f1);

    float s0 = __builtin_amdgcn_sinf(r0);   // sin(2*pi*r0)
    float c0 = __builtin_amdgcn_cosf(r0);
    float s1 = __builtin_amdgcn_sinf(r1);
    float c1 = __builtin_amdgcn_cosf(r1);

    vf4 v = __builtin_nontemporal_load(&x4[i]);
    vf4 o;
    o.x = c0 * v.x - s0 * v.y;
    o.y = s0 * v.x + c0 * v.y;
    o.z = c1 * v.z - s1 * v.w;
    o.w = s1 * v.z + c1 * v.w;
    __builtin_nontemporal_store(o, &out4[i]);
}

extern "C" void kernel_launch(void* const* d_in, const int* in_sizes, int n_in,
                              void* d_out, int out_size, void* d_ws, size_t ws_size,
                              hipStream_t stream) {
    const vf4* x4  = (const vf4*)d_in[0];
    const int* pos = (const int*)d_in[1];
    vf4*       o4  = (vf4*)d_out;

    int n   = in_sizes[0];       // total fp32 elements of x (4*4096*128)
    int seq = in_sizes[1];       // 4096
    int n4  = n / 4;             // 524288 float4s

    int block = 256;
    int grid  = (n4 + block - 1) / block;   // 2048 blocks = 8 per CU

    if ((seq & (seq - 1)) == 0) {
        rope_kernel<true ><<<grid, block, 0, stream>>>(x4, pos, o4, n4, seq - 1);
    } else {
        rope_kernel<false><<<grid, block, 0, stream>>>(x4, pos, o4, n4, seq);
    }
}